// Round 1
// baseline (349.778 us; speedup 1.0000x reference)
//
#include <hip/hip_runtime.h>
#include <hip/hip_bf16.h>

// PhraseClassifier fused kernel for MI355X (gfx950).
// Pipeline: count_pos -> w1_transpose(fp32->bf16, [K][N]->[N][K]) -> fused
// gather+GEMM(bf16 MFMA 16x16x32)+relu+dot(W2)+sigmoid+BCE+reduce.

typedef float f32x4 __attribute__((ext_vector_type(4)));
typedef __bf16 bf16x8 __attribute__((ext_vector_type(8)));

__device__ __forceinline__ unsigned short f2bf(float f) {
  unsigned int u = __float_as_uint(f);
  u += 0x7fffu + ((u >> 16) & 1u);   // RNE
  return (unsigned short)(u >> 16);
}

// ---------------- prep 1: n_pos = sum(flags == 1) ----------------
__global__ void count_pos(const int* __restrict__ flags, int n, int* __restrict__ np) {
  int i = blockIdx.x * 256 + threadIdx.x;
  int c = (i < n && flags[i] == 1) ? 1 : 0;
  unsigned long long m = __ballot(c);
  if ((threadIdx.x & 63) == 0) atomicAdd(np, (int)__popcll(m));
}

// ---------------- prep 2: W1 [1024][512] fp32 -> W1t [512][1024] bf16 ----------------
__global__ void w1_transpose(const float* __restrict__ W1, unsigned short* __restrict__ W1t) {
  __shared__ float tile[32][33];
  int k0 = blockIdx.x * 32, n0 = blockIdx.y * 32;
  int tx = threadIdx.x, ty = threadIdx.y;  // 32 x 8
#pragma unroll
  for (int r = 0; r < 4; ++r)
    tile[ty + r * 8][tx] = W1[(k0 + ty + r * 8) * 512 + n0 + tx];
  __syncthreads();
#pragma unroll
  for (int r = 0; r < 4; ++r)
    W1t[(n0 + ty + r * 8) * 1024 + k0 + tx] = f2bf(tile[tx][ty + r * 8]);
}

// ---------------- main fused kernel ----------------
// Block: 256 threads (4 waves). Tile: 64 spans x 512 cols (full N -> fuse epilogue).
// K-loop: 32 iters of BK=32. Wave w handles cols [w*128, w*128+128): 4m x 8n MFMA tiles.
#define TM 64
__global__ __launch_bounds__(256, 2) void fused_main(
    const float* __restrict__ hidden,     // [512][32][1024]
    const int* __restrict__ bids, const int* __restrict__ begins,
    const int* __restrict__ ends, const int* __restrict__ flags,
    const float* __restrict__ weights,
    const unsigned short* __restrict__ w1t,  // [512][1024] bf16
    const float* __restrict__ b1, const float* __restrict__ w2,
    const float* __restrict__ b2, const int* __restrict__ npos,
    float* __restrict__ out, int nspans) {
  // A: 64 rows x 32 cols bf16, row stride 40 (+8 pad -> 2-way max conflicts)
  __shared__ __align__(16) unsigned short Ab[TM * 40];
  // B: 512 n-rows x 32 k bf16, chunk-XOR-swizzled (global_load_lds friendly)
  __shared__ __align__(16) unsigned short Bb[512 * 32];
  __shared__ int4 meta[TM];
  __shared__ float lg[TM];

  const int t = threadIdx.x;
  const int lane = t & 63;
  const int w = t >> 6;                 // wave 0..3 -> col block w*128
  const int s0 = blockIdx.x * TM;

  if (t < TM) {
    int s = s0 + t;
    int b = bids[s], bg = begins[s], en = ends[s];
    // hidden row bases (elements): fwd uses rows end-1, begin-1 (cols 0..511);
    // bwd uses rows begin, end (cols 512..1023). value = row0 - row1.
    meta[t] = make_int4((((en - 1) << 5) + b) << 10, (((bg - 1) << 5) + b) << 10,
                        (((bg) << 5) + b) << 10, (((en) << 5) + b) << 10);
    lg[t] = 0.0f;
  }

  f32x4 acc[4][8];
#pragma unroll
  for (int i = 0; i < 4; ++i)
#pragma unroll
    for (int j = 0; j < 8; ++j) acc[i][j] = (f32x4){0.f, 0.f, 0.f, 0.f};

  __syncthreads();

  const int ar = t >> 2;            // A stage: row 0..63
  const int acg = (t & 3) << 3;     // col group offset 0/8/16/24

  for (int it = 0; it < 32; ++it) {
    const int k0 = it << 5;

    // ---- B stage: async global->LDS, 8 issues/wave, 16 n-rows per issue.
    // LDS slot c holds logical chunk (c ^ (n&3)) (self-inverse swizzle).
#pragma unroll
    for (int q = 0; q < 8; ++q) {
      int n = (w << 7) + (q << 4) + (lane >> 2);
      int cs = (lane & 3) ^ (n & 3);
      const unsigned short* gp = w1t + n * 1024 + k0 + (cs << 3);
      unsigned short* lp = &Bb[(((w << 7) + (q << 4)) << 5)];  // wave-uniform base
      __builtin_amdgcn_global_load_lds(
          (const __attribute__((address_space(1))) void*)gp,
          (__attribute__((address_space(3))) void*)lp, 16, 0, 0);
    }

    // ---- A stage: gather two hidden rows, diff, cvt bf16, 16B LDS write
    {
      int4 m = meta[ar];
      int rX = (k0 < 512) ? m.x : m.z;
      int rY = (k0 < 512) ? m.y : m.w;
      const float4* pX = (const float4*)(hidden + rX + k0 + acg);
      const float4* pY = (const float4*)(hidden + rY + k0 + acg);
      float4 x0 = pX[0], x1 = pX[1];
      float4 y0 = pY[0], y1 = pY[1];
      uint4 pk;
      pk.x = (unsigned)f2bf(x0.x - y0.x) | ((unsigned)f2bf(x0.y - y0.y) << 16);
      pk.y = (unsigned)f2bf(x0.z - y0.z) | ((unsigned)f2bf(x0.w - y0.w) << 16);
      pk.z = (unsigned)f2bf(x1.x - y1.x) | ((unsigned)f2bf(x1.y - y1.y) << 16);
      pk.w = (unsigned)f2bf(x1.z - y1.z) | ((unsigned)f2bf(x1.w - y1.w) << 16);
      *(uint4*)((char*)Ab + ar * 80 + (t & 3) * 16) = pk;
    }
    __syncthreads();

    // ---- compute: frag loads (ds_read_b128) + 32 MFMAs
    bf16x8 af[4], bfr[8];
#pragma unroll
    for (int mt = 0; mt < 4; ++mt) {
      int row = (mt << 4) + (lane & 15);
      af[mt] = *(const bf16x8*)((const char*)Ab + row * 80 + ((lane >> 4) << 4));
    }
#pragma unroll
    for (int nt = 0; nt < 8; ++nt) {
      int n = (w << 7) + (nt << 4) + (lane & 15);
      int cs = (lane >> 4) ^ (n & 3);
      bfr[nt] = *(const bf16x8*)((const char*)Bb + n * 64 + (cs << 4));
    }
#pragma unroll
    for (int mt = 0; mt < 4; ++mt)
#pragma unroll
      for (int nt = 0; nt < 8; ++nt)
        acc[mt][nt] = __builtin_amdgcn_mfma_f32_16x16x32_bf16(af[mt], bfr[nt],
                                                              acc[mt][nt], 0, 0, 0);
    __syncthreads();
  }

  // ---- epilogue: z = relu(acc + b1); partial logit = sum_j z*W2[j]
  // C/D layout: col = lane&15, row = (lane>>4)*4 + reg  [verified m89/m91]
  float b1v[8], w2v[8];
#pragma unroll
  for (int nt = 0; nt < 8; ++nt) {
    int j = (w << 7) + (nt << 4) + (lane & 15);
    b1v[nt] = b1[j];
    w2v[nt] = w2[j];
  }
#pragma unroll
  for (int mt = 0; mt < 4; ++mt) {
#pragma unroll
    for (int r = 0; r < 4; ++r) {
      float sv = 0.f;
#pragma unroll
      for (int nt = 0; nt < 8; ++nt) {
        float z = acc[mt][nt][r] + b1v[nt];
        z = fmaxf(z, 0.f);
        sv += z * w2v[nt];
      }
      // reduce over the 16 lanes that share these rows (cols)
      sv += __shfl_xor(sv, 1);
      sv += __shfl_xor(sv, 2);
      sv += __shfl_xor(sv, 4);
      sv += __shfl_xor(sv, 8);
      if ((lane & 15) == 0)
        atomicAdd(&lg[(mt << 4) + ((lane >> 4) << 2) + r], sv);
    }
  }
  __syncthreads();

  // ---- per-span BCE + block reduction (threads 0..63 = wave 0)
  if (t < TM) {
    int s = s0 + t;
    float logit = lg[t] + b2[0];
    float p = 1.f / (1.f + expf(-logit));
    p = fminf(fmaxf(p, 1e-7f), 1.f - 1e-7f);
    int fl = flags[s];
    float npf = (float)(*npos);
    float scale = 2.f * npf / (float)nspans;
    float bce = (fl == 1) ? -logf(p) : -logf(1.f - p);
    float wv = weights[s] * ((fl == 1) ? 1.f : scale);
    float term = wv * bce / (float)nspans;
#pragma unroll
    for (int off = 32; off > 0; off >>= 1) term += __shfl_down(term, off);
    if (t == 0) atomicAdd(out, term);
  }
}

extern "C" void kernel_launch(void* const* d_in, const int* in_sizes, int n_in,
                              void* d_out, int out_size, void* d_ws, size_t ws_size,
                              hipStream_t stream) {
  const float* hidden = (const float*)d_in[0];
  const int* bids     = (const int*)d_in[1];
  const int* begins   = (const int*)d_in[2];
  const int* ends     = (const int*)d_in[3];
  const int* flags    = (const int*)d_in[4];
  const float* weights = (const float*)d_in[5];
  const float* W1 = (const float*)d_in[6];
  const float* b1 = (const float*)d_in[7];
  const float* W2 = (const float*)d_in[8];
  const float* b2 = (const float*)d_in[9];
  float* out = (float*)d_out;
  const int nspans = in_sizes[1];  // 131072

  int* npos = (int*)d_ws;
  unsigned short* W1t = (unsigned short*)((char*)d_ws + 256);  // 1 MiB bf16

  hipMemsetAsync(d_ws, 0, 256, stream);               // zero n_pos
  hipMemsetAsync(d_out, 0, sizeof(float), stream);    // out is atomically accumulated

  count_pos<<<(nspans + 255) / 256, 256, 0, stream>>>(flags, nspans, npos);
  w1_transpose<<<dim3(32, 16), dim3(32, 8), 0, stream>>>(W1, W1t);
  fused_main<<<nspans / TM, 256, 0, stream>>>(hidden, bids, begins, ends, flags,
                                              weights, W1t, b1, W2, b2, npos, out,
                                              nspans);
}

// Round 2
// 343.393 us; speedup vs baseline: 1.0186x; 1.0186x over previous
//
#include <hip/hip_runtime.h>
#include <hip/hip_bf16.h>

// PhraseClassifier fused kernel for MI355X (gfx950), R2: software-pipelined
// K-loop (double-buffered LDS, 1 barrier/iter), fixed B bank swizzle,
// count_pos folded into main (pos/neg partial sums + npos), finalize kernel.

typedef float f32x4 __attribute__((ext_vector_type(4)));
typedef __bf16 bf16x8 __attribute__((ext_vector_type(8)));

__device__ __forceinline__ unsigned short f2bf(float f) {
  unsigned int u = __float_as_uint(f);
  u += 0x7fffu + ((u >> 16) & 1u);   // RNE
  return (unsigned short)(u >> 16);
}

// ---------------- prep: W1 [1024][512] fp32 -> W1t [512][1024] bf16 ----------------
__global__ void w1_transpose(const float* __restrict__ W1, unsigned short* __restrict__ W1t) {
  __shared__ float tile[32][33];
  int k0 = blockIdx.x * 32, n0 = blockIdx.y * 32;
  int tx = threadIdx.x, ty = threadIdx.y;  // 32 x 8
#pragma unroll
  for (int r = 0; r < 4; ++r)
    tile[ty + r * 8][tx] = W1[(k0 + ty + r * 8) * 512 + n0 + tx];
  __syncthreads();
#pragma unroll
  for (int r = 0; r < 4; ++r)
    W1t[(n0 + ty + r * 8) * 1024 + k0 + tx] = f2bf(tile[tx][ty + r * 8]);
}

// ---------------- main fused kernel ----------------
// Block: 256 threads (4 waves). Tile: 64 spans x full 512 cols.
// Pipelined K-loop: BK=32, 32 iters, double-buffered A/B LDS, one barrier/iter.
#define TM 64
__global__ __launch_bounds__(256, 2) void fused_main(
    const float* __restrict__ hidden,     // [512][32][1024]
    const int* __restrict__ bids, const int* __restrict__ begins,
    const int* __restrict__ ends, const int* __restrict__ flags,
    const float* __restrict__ weights,
    const unsigned short* __restrict__ w1t,  // [512][1024] bf16
    const float* __restrict__ b1, const float* __restrict__ w2,
    const float* __restrict__ b2,
    float* __restrict__ wsf, int* __restrict__ wsi, int nspans) {
  // A: 64 rows x 32 k bf16, row stride 40 shorts (80B: rows r,r+8 alias -> 2-way, free)
  __shared__ __align__(16) unsigned short Ab[2][TM * 40];
  // B: 512 n-rows x 32 k bf16, 64B/row; 16B chunk c holds logical chunk c^((n>>1)&3)
  // -> read bank-quad = 16(n&1)+4((n>>1)&3): bijective over 8 quads -> 2-way only.
  __shared__ __align__(16) unsigned short Bb[2][512 * 32];
  __shared__ int4 meta_s[TM];
  __shared__ float lg[TM];

  const int t = threadIdx.x;
  const int lane = t & 63;
  const int w = t >> 6;                 // wave 0..3 -> col block w*128
  const int s0 = blockIdx.x * TM;

  if (t < TM) {
    int s = s0 + t;
    int b = bids[s], bg = begins[s], en = ends[s];
    // element base offsets of the 4 gathered hidden rows (row = (seq*32+b)*1024)
    meta_s[t] = make_int4((((en - 1) << 5) + b) << 10, (((bg - 1) << 5) + b) << 10,
                          ((bg << 5) + b) << 10, ((en << 5) + b) << 10);
    lg[t] = 0.0f;
  }

  f32x4 acc[4][8];
#pragma unroll
  for (int i = 0; i < 4; ++i)
#pragma unroll
    for (int j = 0; j < 8; ++j) acc[i][j] = (f32x4){0.f, 0.f, 0.f, 0.f};

  __syncthreads();

  const int ar = t >> 2;            // A stage: my span row
  const int acg = (t & 3) << 3;     // my k-chunk offset within BK (0/8/16/24)
  const int4 mreg = meta_s[ar];     // hoisted: constant across K iters

  // B global offsets (elements), constant across K except +k0
  int boff[8];
#pragma unroll
  for (int q = 0; q < 8; ++q) {
    int n = (w << 7) + (q << 4) + (lane >> 2);
    int sc = (lane & 3) ^ ((n >> 1) & 3);   // source chunk for my LDS slot
    boff[q] = n * 1024 + (sc << 3);
  }

  auto prefetchB = [&](int k0, int buf) {
#pragma unroll
    for (int q = 0; q < 8; ++q) {
      const unsigned short* gp = w1t + boff[q] + k0;
      unsigned short* lp = &Bb[buf][((w << 7) + (q << 4)) << 5];  // wave-uniform base
      __builtin_amdgcn_global_load_lds(
          (const __attribute__((address_space(1))) void*)gp,
          (__attribute__((address_space(3))) void*)lp, 16, 0, 0);
    }
  };
  auto gatherA = [&](int k0, float4& x0, float4& x1, float4& y0, float4& y1) {
    int rX = (k0 < 512) ? mreg.x : mreg.z;  // fwd: end-1 / begin-1; bwd: begin / end
    int rY = (k0 < 512) ? mreg.y : mreg.w;
    const float4* pX = (const float4*)(hidden + rX + k0 + acg);
    const float4* pY = (const float4*)(hidden + rY + k0 + acg);
    x0 = pX[0]; x1 = pX[1]; y0 = pY[0]; y1 = pY[1];
  };
  auto writeA = [&](int buf, const float4& x0, const float4& x1,
                    const float4& y0, const float4& y1) {
    uint4 pk;
    pk.x = (unsigned)f2bf(x0.x - y0.x) | ((unsigned)f2bf(x0.y - y0.y) << 16);
    pk.y = (unsigned)f2bf(x0.z - y0.z) | ((unsigned)f2bf(x0.w - y0.w) << 16);
    pk.z = (unsigned)f2bf(x1.x - y1.x) | ((unsigned)f2bf(x1.y - y1.y) << 16);
    pk.w = (unsigned)f2bf(x1.z - y1.z) | ((unsigned)f2bf(x1.w - y1.w) << 16);
    *(uint4*)((char*)Ab[buf] + ar * 80 + (t & 3) * 16) = pk;
  };

  // ---- pipeline preamble: stage tile 0
  float4 x0, x1, y0, y1;
  gatherA(0, x0, x1, y0, y1);       // A first -> its wait is vmcnt(8), not vmcnt(0)
  prefetchB(0, 0);
  writeA(0, x0, x1, y0, y1);
  __syncthreads();

#pragma unroll 2
  for (int it = 0; it < 32; ++it) {
    const int buf = it & 1;
    if (it < 31) {
      gatherA((it + 1) << 5, x0, x1, y0, y1);  // regs, lands during MFMAs
      prefetchB((it + 1) << 5, buf ^ 1);       // async LDS, drains at barrier
    }

    bf16x8 af[4], bfr[8];
#pragma unroll
    for (int mt = 0; mt < 4; ++mt) {
      int row = (mt << 4) + (lane & 15);
      af[mt] = *(const bf16x8*)((const char*)Ab[buf] + row * 80 + ((lane >> 4) << 4));
    }
#pragma unroll
    for (int nt = 0; nt < 8; ++nt) {
      int n = (w << 7) + (nt << 4) + (lane & 15);
      int cs = (lane >> 4) ^ ((n >> 1) & 3);
      bfr[nt] = *(const bf16x8*)((const char*)Bb[buf] + n * 64 + (cs << 4));
    }
#pragma unroll
    for (int mt = 0; mt < 4; ++mt)
#pragma unroll
      for (int nt = 0; nt < 8; ++nt)
        acc[mt][nt] = __builtin_amdgcn_mfma_f32_16x16x32_bf16(af[mt], bfr[nt],
                                                              acc[mt][nt], 0, 0, 0);
    if (it < 31) writeA(buf ^ 1, x0, x1, y0, y1);
    __syncthreads();
  }

  // ---- epilogue: z = relu(acc + b1); logit partial = sum_j z*W2[j]
  // C/D layout: col = lane&15, row = (lane>>4)*4 + reg  [m89/m91]
  float b1v[8], w2v[8];
#pragma unroll
  for (int nt = 0; nt < 8; ++nt) {
    int j = (w << 7) + (nt << 4) + (lane & 15);
    b1v[nt] = b1[j];
    w2v[nt] = w2[j];
  }
#pragma unroll
  for (int mt = 0; mt < 4; ++mt) {
#pragma unroll
    for (int r = 0; r < 4; ++r) {
      float sv = 0.f;
#pragma unroll
      for (int nt = 0; nt < 8; ++nt) {
        float z = acc[mt][nt][r] + b1v[nt];
        z = fmaxf(z, 0.f);
        sv += z * w2v[nt];
      }
      sv += __shfl_xor(sv, 1);
      sv += __shfl_xor(sv, 2);
      sv += __shfl_xor(sv, 4);
      sv += __shfl_xor(sv, 8);
      if ((lane & 15) == 0)
        atomicAdd(&lg[(mt << 4) + ((lane >> 4) << 2) + r], sv);
    }
  }
  __syncthreads();

  // ---- per-span BCE; block accumulates pos_sum / neg_sum / npos (wave 0 only)
  if (t < TM) {
    int s = s0 + t;
    float logit = lg[t] + b2[0];
    float p = 1.f / (1.f + expf(-logit));
    p = fminf(fmaxf(p, 1e-7f), 1.f - 1e-7f);
    int fl = flags[s];
    float bce = (fl == 1) ? -logf(p) : -logf(1.f - p);
    float term = weights[s] * bce;
    float pos_t = (fl == 1) ? term : 0.f;
    float neg_t = (fl == 1) ? 0.f : term;
    unsigned long long m = __ballot(fl == 1);
#pragma unroll
    for (int off = 32; off > 0; off >>= 1) {
      pos_t += __shfl_down(pos_t, off);
      neg_t += __shfl_down(neg_t, off);
    }
    if (t == 0) {
      atomicAdd(&wsf[0], pos_t);
      atomicAdd(&wsf[1], neg_t);
      atomicAdd(&wsi[2], (int)__popcll(m));
    }
  }
}

// ---------------- finalize: combine pos/neg sums with class-rebalance scale ----
__global__ void finalize(const float* __restrict__ wsf, const int* __restrict__ wsi,
                         float* __restrict__ out, int nspans) {
  float pos = wsf[0], neg = wsf[1];
  float npf = (float)wsi[2];
  float scale = 2.f * npf / (float)nspans;
  out[0] = (pos + scale * neg) / (float)nspans;
}

extern "C" void kernel_launch(void* const* d_in, const int* in_sizes, int n_in,
                              void* d_out, int out_size, void* d_ws, size_t ws_size,
                              hipStream_t stream) {
  const float* hidden = (const float*)d_in[0];
  const int* bids     = (const int*)d_in[1];
  const int* begins   = (const int*)d_in[2];
  const int* ends     = (const int*)d_in[3];
  const int* flags    = (const int*)d_in[4];
  const float* weights = (const float*)d_in[5];
  const float* W1 = (const float*)d_in[6];
  const float* b1 = (const float*)d_in[7];
  const float* W2 = (const float*)d_in[8];
  const float* b2 = (const float*)d_in[9];
  float* out = (float*)d_out;
  const int nspans = in_sizes[1];  // 131072

  float* wsf = (float*)d_ws;                                   // [0]=pos,[1]=neg
  int* wsi = (int*)d_ws;                                       // [2]=npos
  unsigned short* W1t = (unsigned short*)((char*)d_ws + 256);  // 1 MiB bf16

  hipMemsetAsync(d_ws, 0, 256, stream);

  w1_transpose<<<dim3(32, 16), dim3(32, 8), 0, stream>>>(W1, W1t);
  fused_main<<<nspans / TM, 256, 0, stream>>>(hidden, bids, begins, ends, flags,
                                              weights, W1t, b1, W2, b2, wsf, wsi,
                                              nspans);
  finalize<<<1, 1, 0, stream>>>(wsf, wsi, out, nspans);
}